// Round 13
// baseline (227.062 us; speedup 1.0000x reference)
//
#include <hip/hip_runtime.h>
#include <hip/hip_bf16.h>
#include <hip/hip_fp16.h>

// Problem constants
#define DIMSZ 1024
#define HEADS 16
#define HD 64
#define BATCH 2
#define SEQ 2048
#define MROWS (BATCH*SEQ)   // 4096

typedef _Float16 f16;
typedef _Float16 f16x8 __attribute__((ext_vector_type(8)));
typedef float f32x4 __attribute__((ext_vector_type(4)));
typedef float f32x16 __attribute__((ext_vector_type(16)));

__device__ __forceinline__ void gload_lds16(const void* g, void* l) {
  // 16B direct global->LDS: dest = wave-uniform base + lane*16
  __builtin_amdgcn_global_load_lds(
      (const __attribute__((address_space(1))) unsigned int*)g,
      (__attribute__((address_space(3))) unsigned int*)l, 16, 0, 0);
}

// ---------------- fp32 -> fp16 elementwise (x) ----------------
__global__ __launch_bounds__(256) void k_cvt_x(const float* __restrict__ in,
                                               f16* __restrict__ out) {
  int i = blockIdx.x * 256 + threadIdx.x;   // 4096*1024/4 elems of float4
  float4 v = ((const float4*)in)[i];
  union { f16 h[4]; uint2 u; } p;
  p.h[0] = (f16)v.x; p.h[1] = (f16)v.y; p.h[2] = (f16)v.z; p.h[3] = (f16)v.w;
  ((uint2*)out)[i] = p.u;
}

// ---------------- fp32 [R][C] -> fp16 [C][R] transpose ----------------
__global__ __launch_bounds__(256) void k_tcvt(const float* __restrict__ in,
                                              f16* __restrict__ out,
                                              int R, int C) {
  __shared__ f16 t[64][66];  // +2 pad: conflict-free col reads
  int c0 = blockIdx.x * 64, r0 = blockIdx.y * 64;
  int tid = threadIdx.x;
  int cc = tid & 63;
  #pragma unroll
  for (int p = 0; p < 16; p++) {
    int r = p * 4 + (tid >> 6);
    t[r][cc] = (f16)in[(size_t)(r0 + r) * C + c0 + cc];
  }
  __syncthreads();
  int rr = tid & 63;
  #pragma unroll
  for (int p = 0; p < 16; p++) {
    int c = p * 4 + (tid >> 6);
    out[(size_t)(c0 + c) * R + r0 + rr] = t[rr][c];
  }
}

// ---------------- GEMM core (shared shape): C[128x128] tile, BK=64 ----------
// A: [M][1024] fp16 row-major, Bt: [N][1024] fp16 row-major (i.e. B transposed)
// 256 threads = 4 waves in 2x2, each wave 64x64 (4x4 frags of 16x16x32_f16)
#define GEMM_CORE(Aptr, Bptr)                                                  \
  __shared__ __align__(16) f16 As[128 * 64];                                   \
  __shared__ __align__(16) f16 Bs[128 * 64];                                   \
  const int K = 1024;                                                          \
  int tid = threadIdx.x, l = tid & 63, w = tid >> 6;                           \
  int bm = blockIdx.y, bn = blockIdx.x;                                        \
  int wr = (w >> 1) * 64, wc = (w & 1) * 64;                                   \
  const f16* Ag = (Aptr) + (size_t)bm * 128 * K;                               \
  const f16* Bg = (Bptr) + (size_t)bn * 128 * K;                               \
  f32x4 acc[4][4] = {};                                                        \
  for (int kt = 0; kt < K; kt += 64) {                                         \
    __syncthreads();                                                           \
    _Pragma("unroll")                                                          \
    for (int i = 0; i < 4; i++) {                                              \
      int base = i * 256 + w * 64;                                             \
      int chunk = base + l;                                                    \
      int row = chunk >> 3, c = chunk & 7, sc = c ^ (row & 7);                 \
      gload_lds16(Ag + (size_t)row * K + kt + sc * 8, &As[base * 8]);          \
    }                                                                          \
    _Pragma("unroll")                                                          \
    for (int i = 0; i < 4; i++) {                                              \
      int base = i * 256 + w * 64;                                             \
      int chunk = base + l;                                                    \
      int row = chunk >> 3, c = chunk & 7, sc = c ^ (row & 7);                 \
      gload_lds16(Bg + (size_t)row * K + kt + sc * 8, &Bs[base * 8]);          \
    }                                                                          \
    __syncthreads();                                                           \
    f16x8 af[4][2], bf[4][2];                                                  \
    _Pragma("unroll")                                                          \
    for (int m = 0; m < 4; m++)                                                \
      _Pragma("unroll")                                                        \
      for (int kk = 0; kk < 2; kk++) {                                         \
        int row = wr + m * 16 + (l & 15);                                      \
        int pc = (kk * 4 + (l >> 4)) ^ (row & 7);                              \
        af[m][kk] = *(const f16x8*)&As[row * 64 + pc * 8];                     \
      }                                                                        \
    _Pragma("unroll")                                                          \
    for (int n = 0; n < 4; n++)                                                \
      _Pragma("unroll")                                                        \
      for (int kk = 0; kk < 2; kk++) {                                         \
        int row = wc + n * 16 + (l & 15);                                      \
        int pc = (kk * 4 + (l >> 4)) ^ (row & 7);                              \
        bf[n][kk] = *(const f16x8*)&Bs[row * 64 + pc * 8];                     \
      }                                                                        \
    _Pragma("unroll")                                                          \
    for (int m = 0; m < 4; m++)                                                \
      _Pragma("unroll")                                                        \
      for (int n = 0; n < 4; n++)                                              \
        _Pragma("unroll")                                                      \
        for (int kk = 0; kk < 2; kk++)                                         \
          acc[m][n] = __builtin_amdgcn_mfma_f32_16x16x32_f16(af[m][kk],        \
                          bf[n][kk], acc[m][n], 0, 0, 0);                      \
  }

// QKV projection: writes Q,K as [B*H][SEQ][64] fp16, V as [B*H][64][SEQ] fp16
__global__ __launch_bounds__(256) void k_gemm_qkv(
    const f16* __restrict__ A, const f16* __restrict__ Bt,
    const float* __restrict__ bias,
    f16* __restrict__ qb, f16* __restrict__ kb, f16* __restrict__ vb) {
  GEMM_CORE(A, Bt)
  int gm0 = bm * 128 + wr;
  int gn0 = bn * 128 + wc;
  #pragma unroll
  for (int n = 0; n < 4; n++) {
    int col = gn0 + n * 16 + (l & 15);
    float bv = bias[col];
    int which = col >> 10, rest = col & 1023, h = rest >> 6, d = rest & 63;
    #pragma unroll
    for (int m = 0; m < 4; m++) {
      int rowb = gm0 + m * 16 + ((l >> 4) << 2);
      int b = rowb >> 11, nn = rowb & 2047;
      if (which == 2) {
        union { f16 h[4]; uint2 u; } pk;
        #pragma unroll
        for (int j = 0; j < 4; j++) pk.h[j] = (f16)(acc[m][n][j] + bv);
        *(uint2*)(vb + ((size_t)(b * HEADS + h) * 64 + d) * SEQ + nn) = pk.u;
      } else {
        f16* dst = (which ? kb : qb) + ((size_t)(b * HEADS + h) * SEQ + nn) * 64 + d;
        #pragma unroll
        for (int j = 0; j < 4; j++) dst[(size_t)j * 64] = (f16)(acc[m][n][j] + bv);
      }
    }
  }
}

// Output projection: ctx[4096][1024] fp16 @ Wout^T -> fp32 out + bias
__global__ __launch_bounds__(256) void k_gemm_out(
    const f16* __restrict__ A, const f16* __restrict__ Bt,
    const float* __restrict__ bias, float* __restrict__ out) {
  GEMM_CORE(A, Bt)
  int gm0 = bm * 128 + wr;
  int gn0 = bn * 128 + wc;
  #pragma unroll
  for (int n = 0; n < 4; n++) {
    int col = gn0 + n * 16 + (l & 15);
    float bv = bias[col];
    #pragma unroll
    for (int m = 0; m < 4; m++) {
      int rowb = gm0 + m * 16 + ((l >> 4) << 2);
      #pragma unroll
      for (int j = 0; j < 4; j++)
        out[(size_t)(rowb + j) * DIMSZ + col] = acc[m][n][j] + bv;
    }
  }
}

// ---------------- Flash attention (v3: 32x32 MFMA, P in registers) --------
// 256 threads = 4 waves, each wave owns 32 q (block = 128 q). grid 512.
// KV-tile = 64 keys, double-buffered, prefetch-before-compute.
// S^T = mfma_32x32x16(K, Q): lane holds col q = lane&31, 32 kv rows.
// Softmax reduce: 31 in-lane max + ONE shfl_xor(32). P converted to the PV
// B-operand entirely in registers: 4x v_cvt_pkrtz + 2x v_permlane32_swap
// per 16-kv step (no LDS for P). O^T = mfma(V^T, P^T).
__global__ __launch_bounds__(256) void k_attn(
    const f16* __restrict__ qb, const f16* __restrict__ kb,
    const f16* __restrict__ vb, f16* __restrict__ ctx) {
  __shared__ __align__(16) f16 Ks[2][64 * 64];
  __shared__ __align__(16) f16 Vs[2][64 * 64];   // V^T tile: [d][kv]
  int tid = threadIdx.x, l = tid & 63, w = tid >> 6;
  int lq = l & 31, hh = l >> 5;   // q column; k-half (8-elem group)
  int qtile = blockIdx.x & 15, bh = blockIdx.x >> 4;

  const f16* Kg = kb + (size_t)bh * SEQ * 64;
  const f16* Vg = vb + (size_t)bh * 64 * SEQ;

  // Q B-frags: B[k][q], q = lq, k = st*16 + hh*8 + j
  const f16* Qrow = qb + ((size_t)bh * SEQ + qtile * 128 + w * 32 + lq) * 64;
  f16x8 qf[4];
  #pragma unroll
  for (int st = 0; st < 4; st++)
    qf[st] = *(const f16x8*)(Qrow + st * 16 + hh * 8);

  f32x16 o0 = {}, o1 = {};
  float mrun = -INFINITY, lrun = 0.f;
  const float SC = 0.125f * 1.44269504f;  // 1/sqrt(64) folded into exp2

  // staging: 256 threads x 2 chunks x 16B per 64x64 tile (K and V)
  int ch0 = tid, ch1 = tid + 256;
  int r0 = ch0 >> 3, c0 = (ch0 & 7) ^ (r0 & 7);
  int r1 = ch1 >> 3, c1 = (ch1 & 7) ^ (r1 & 7);
  const f16* K0 = Kg + (size_t)r0 * 64 + c0 * 8;
  const f16* K1 = Kg + (size_t)r1 * 64 + c1 * 8;
  const f16* V0 = Vg + (size_t)r0 * SEQ + c0 * 8;
  const f16* V1 = Vg + (size_t)r1 * SEQ + c1 * 8;

#define ATTN_STAGE(t, b) do {                                     \
    gload_lds16(K0 + (size_t)(t) * 4096, &Ks[b][w * 512]);        \
    gload_lds16(K1 + (size_t)(t) * 4096, &Ks[b][2048 + w * 512]); \
    gload_lds16(V0 + (size_t)(t) * 64,   &Vs[b][w * 512]);        \
    gload_lds16(V1 + (size_t)(t) * 64,   &Vs[b][2048 + w * 512]); \
  } while (0)

  ATTN_STAGE(0, 0);
  __syncthreads();

  for (int t = 0; t < 32; t++) {
    int cur = t & 1;
    if (t < 31) ATTN_STAGE(t + 1, cur ^ 1);   // prefetch hides HBM latency

    // S^T = K * Q
    f32x16 s0 = {}, s1 = {};
    __builtin_amdgcn_s_setprio(1);
    #pragma unroll
    for (int st = 0; st < 4; st++) {
      int ch = st * 2 + hh;
      int sw = (ch ^ (lq & 7)) * 8;
      f16x8 ka0 = *(const f16x8*)&Ks[cur][lq * 64 + sw];
      f16x8 ka1 = *(const f16x8*)&Ks[cur][(32 + lq) * 64 + sw];
      s0 = __builtin_amdgcn_mfma_f32_32x32x16_f16(ka0, qf[st], s0, 0, 0, 0);
      s1 = __builtin_amdgcn_mfma_f32_32x32x16_f16(ka1, qf[st], s1, 0, 0, 0);
    }
    __builtin_amdgcn_s_setprio(0);

    // online softmax: lane holds 32 kv values for its q; 1 shfl completes row
    float tm = -INFINITY;
    #pragma unroll
    for (int i = 0; i < 16; i++) tm = fmaxf(tm, fmaxf(s0[i], s1[i]));
    tm = fmaxf(tm, __shfl_xor(tm, 32));
    if (!__all(tm <= mrun)) {          // defer-max: skip rescale if no growth
      float mnew = fmaxf(mrun, tm);
      float corr = __builtin_amdgcn_exp2f(mrun * SC - mnew * SC);
      lrun *= corr;
      #pragma unroll
      for (int i = 0; i < 16; i++) { o0[i] *= corr; o1[i] *= corr; }
      mrun = mnew;
    }
    float a = mrun * SC;
    float ts = 0.f;
    #pragma unroll
    for (int i = 0; i < 16; i++) {
      s0[i] = __builtin_amdgcn_exp2f(s0[i] * SC - a);
      s1[i] = __builtin_amdgcn_exp2f(s1[i] * SC - a);
      ts += s0[i] + s1[i];
    }
    ts += __shfl_xor(ts, 32);
    lrun += ts;

    // P^T -> PV B-operand frags, entirely in registers (cvt_pkrtz + permlane)
    f16x8 pb[4];
    #pragma unroll
    for (int ks = 0; ks < 4; ks++) {
      const f32x16& sv = (ks < 2) ? s0 : s1;
      const int rb = (ks & 1) * 8;
      uint c01, c23, c45, c67;
      asm("v_cvt_pkrtz_f16_f32 %0, %1, %2" : "=v"(c01) : "v"(sv[rb + 0]), "v"(sv[rb + 1]));
      asm("v_cvt_pkrtz_f16_f32 %0, %1, %2" : "=v"(c23) : "v"(sv[rb + 2]), "v"(sv[rb + 3]));
      asm("v_cvt_pkrtz_f16_f32 %0, %1, %2" : "=v"(c45) : "v"(sv[rb + 4]), "v"(sv[rb + 5]));
      asm("v_cvt_pkrtz_f16_f32 %0, %1, %2" : "=v"(c67) : "v"(sv[rb + 6]), "v"(sv[rb + 7]));
      asm("v_permlane32_swap_b32 %0, %1" : "+v"(c01), "+v"(c45));
      asm("v_permlane32_swap_b32 %0, %1" : "+v"(c23), "+v"(c67));
      union { uint u[4]; f16x8 v; } pu;
      pu.u[0] = c01; pu.u[1] = c23; pu.u[2] = c45; pu.u[3] = c67;
      pb[ks] = pu.v;
    }

    // O^T += V^T * P^T
    __builtin_amdgcn_s_setprio(1);
    #pragma unroll
    for (int ks = 0; ks < 4; ks++) {
      int ch = ks * 2 + hh;
      int sw = (ch ^ (lq & 7)) * 8;
      f16x8 va0 = *(const f16x8*)&Vs[cur][lq * 64 + sw];
      f16x8 va1 = *(const f16x8*)&Vs[cur][(32 + lq) * 64 + sw];
      o0 = __builtin_amdgcn_mfma_f32_32x32x16_f16(va0, pb[ks], o0, 0, 0, 0);
      o1 = __builtin_amdgcn_mfma_f32_32x32x16_f16(va1, pb[ks], o1, 0, 0, 0);
    }
    __builtin_amdgcn_s_setprio(0);

    __syncthreads();  // buffer swap; barrier drain completes the prefetch
  }

  // O^T[d][q]: lane q=lq holds d = {j + 8*gsub + 4*hh} (+32 for o1)
  float inv = 1.0f / lrun;
  int b = bh >> 4, h = bh & 15;
  f16* crow = ctx + ((size_t)(b * SEQ + qtile * 128 + w * 32 + lq)) * DIMSZ
              + h * 64 + 4 * hh;
  #pragma unroll
  for (int gsub = 0; gsub < 4; gsub++) {
    union { f16 h4[4]; uint2 u; } p0, p1;
    #pragma unroll
    for (int j = 0; j < 4; j++) {
      p0.h4[j] = (f16)(o0[gsub * 4 + j] * inv);
      p1.h4[j] = (f16)(o1[gsub * 4 + j] * inv);
    }
    *(uint2*)(crow + gsub * 8) = p0.u;
    *(uint2*)(crow + 32 + gsub * 8) = p1.u;
  }
#undef ATTN_STAGE
}

extern "C" void kernel_launch(void* const* d_in, const int* in_sizes, int n_in,
                              void* d_out, int out_size, void* d_ws, size_t ws_size,
                              hipStream_t stream) {
  const float* x    = (const float*)d_in[0];
  const float* Wqkv = (const float*)d_in[1];
  const float* bqkv = (const float*)d_in[2];
  const float* Wout = (const float*)d_in[3];
  const float* bout = (const float*)d_in[4];
  float* out = (float*)d_out;
  char* ws = (char*)d_ws;

  // workspace layout (bytes); ctx reuses the xh region (xh dead after GEMM1)
  f16* xh    = (f16*)(ws);                  // 8,388,608
  f16* ctx   = xh;
  f16* wqkvt = (f16*)(ws + 8388608);        // 6,291,456
  f16* woutt = (f16*)(ws + 14680064);       // 2,097,152
  f16* qbuf  = (f16*)(ws + 16777216);       // 8,388,608
  f16* kbuf  = (f16*)(ws + 25165824);       // 8,388,608
  f16* vbuf  = (f16*)(ws + 33554432);       // 8,388,608  (end 41,943,040)

  k_cvt_x<<<4096, 256, 0, stream>>>(x, xh);
  k_tcvt<<<dim3(48, 16), 256, 0, stream>>>(Wqkv, wqkvt, DIMSZ, 3 * DIMSZ);
  k_tcvt<<<dim3(16, 16), 256, 0, stream>>>(Wout, woutt, DIMSZ, DIMSZ);
  k_gemm_qkv<<<dim3(24, 32), 256, 0, stream>>>(xh, wqkvt, bqkv, qbuf, kbuf, vbuf);
  k_attn<<<512, 256, 0, stream>>>(qbuf, kbuf, vbuf, ctx);
  k_gemm_out<<<dim3(8, 32), 256, 0, stream>>>(ctx, woutt, bout, out);
}